// Round 9
// baseline (834.480 us; speedup 1.0000x reference)
//
#include <hip/hip_runtime.h>
#include <stdint.h>

// ---------------------------------------------------------------------------
// SNN categorical policy forward (B=1024, C_IN=8, HID=300, OUT=2, T=300)
//
// R9 = R8 (verified bit-exact) + stall removal in the FIR inner loop:
//  - taps read from LDS (ds_read b128/b64, in-order) instead of s_load
//    (SMEM is out-of-order in lgkmcnt -> compiler must emit lgkmcnt(0),
//    defeating any pipeline). 14 DS ops/group <= 15 encodable.
//  - manual 2-stage software pipeline over tap groups: load (x,taps) of
//    group g+1 into the B buffers while FMA-ing group g from A. Named A/B
//    arrays + unroll(disable) on the g-loop -> no LICM tap-hoist (R3-R6
//    spill class), live set ~90 VGPR by construction.
//  - stages of 60 t (15 chunks) == 15 FIR waves -> perfect balance; 5-stage
//    scan/FIR overlap pipeline (wave 0 scans stage s, waves 1-15 FIR s+1).
//  - enc packed to bitmasks once in a pre-kernel (was 5x redundant).
// Numerics byte-identical to verified R2-R8: same tap values & group
// indexing (j ascending), f64 accumulate, exact-f32 spike scans, f64 fc2,
// partitionable threefry head.
// ---------------------------------------------------------------------------

#define NB    1024
#define CIN   8
#define HID   300
#define TLEN  300
#define KTAP  99
#define THETA 10.0f

// K1 LDS layout (bytes):
//  kL    double[108]      [0,    864)
//  xbuf  float[401*64]    [864,  103520)    slot = 101 + s, s in [-101, 299]
//  ubuf  float[2*60*64]   [103520, 134240)
#define LDS_K1 134240

typedef double d2v __attribute__((ext_vector_type(2)));

__device__ __forceinline__ void threefry2x32(uint32_t c0, uint32_t c1,
                                             uint32_t& o0, uint32_t& o1) {
  const uint32_t k0 = 0u, k1 = 42u;
  const uint32_t k2 = k0 ^ k1 ^ 0x1BD11BDAu;
  uint32_t x0 = c0 + k0, x1 = c1 + k1;
#define TFR(r) { x0 += x1; x1 = (x1 << (r)) | (x1 >> (32 - (r))); x1 ^= x0; }
  TFR(13) TFR(15) TFR(26) TFR(6)  x0 += k1; x1 += k2 + 1u;
  TFR(17) TFR(29) TFR(16) TFR(24) x0 += k2; x1 += k0 + 2u;
  TFR(13) TFR(15) TFR(26) TFR(6)  x0 += k0; x1 += k1 + 3u;
  TFR(17) TFR(29) TFR(16) TFR(24) x0 += k1; x1 += k2 + 4u;
  TFR(13) TFR(15) TFR(26) TFR(6)  x0 += k2; x1 += k0 + 5u;
#undef TFR
  o0 = x0; o1 = x1;
}

__device__ __forceinline__ float jax_uniform_from_bits(uint32_t bits) {
  uint32_t fb = (bits >> 9) | 0x3F800000u;
  float f = __uint_as_float(fb) - 1.0f;
  const float tiny = 1.17549435e-38f;
  float u = __fadd_rn(f, tiny);
  return fmaxf(tiny, u);
}

// ==================== Kernel 0a: taps -> global =============================
__global__ void snn_taps_kernel(double* __restrict__ tapsG) {
  const int i = threadIdx.x;
  if (i < 107) {
    const int j = i - 2;                 // tapsG[j+2] = kD[j], 0 outside [1,99]
    double v = 0.0;
    if (j >= 1 && j <= KTAP) {
      float q  = (float)j / 10.0f;
      float ef = (float)exp((double)(1.0f - q));   // same formula as R2-R8
      v = (double)__fmul_rn(q, ef);
    }
    tapsG[i] = v;
  }
}

// ==================== Kernel 0b: enc -> bitmask =============================
__global__ __launch_bounds__(320)
void snn_enc_kernel(const float* __restrict__ enc, uint32_t* __restrict__ encBG) {
  const int b = blockIdx.x, t = threadIdx.x;
  if (t < TLEN) {
    uint32_t m = 0u;
#pragma unroll
    for (int c = 0; c < CIN; ++c)
      if (enc[b * (CIN * TLEN) + c * TLEN + t] != 0.0f) m |= (1u << c);
    encBG[b * TLEN + t] = m;
  }
}

// ======================= Kernel 1: layer-1 SNN ============================
__global__ __launch_bounds__(1024, 1)
void snn_l1_kernel(const float* __restrict__ W1,
                   const double* __restrict__ tapsG,
                   const uint32_t* __restrict__ encBG,
                   unsigned long long* __restrict__ maskG) {
  extern __shared__ char smem[];
  double* kL   = (double*)(smem);            // [108]; kL[j+2]=kD[j]
  float*  xbuf = (float*)(smem + 864);       // [401*64]
  float*  ubuf = (float*)(smem + 103520);    // [2*60*64]

  const int tid  = threadIdx.x;
  const int lane = tid & 63;
  const int wv   = tid >> 6;            // wave 0..15
  const int bh   = blockIdx.x;          // h-chunk [0,5)
  const int b    = blockIdx.y;
  const int h    = bh * 64 + lane;

  if (tid < 107) kL[tid] = tapsG[tid];
  for (int i = tid; i < 101 * 64; i += 1024)   // zero history s in [-101,-1]
    xbuf[i] = 0.0f;
  __syncthreads();

  float w1f[8];
#pragma unroll
  for (int c = 0; c < 8; ++c)
    w1f[c] = (h < HID) ? W1[h * 8 + c] : 0.0f;

  // ---- phase A: x[t][lane] (bit-identical f32 add chain, R5-verified) ----
  for (int t = wv; t < TLEN; t += 16) {
    const uint32_t bits = encBG[__builtin_amdgcn_readfirstlane(b * TLEN + t)];
    float xf = 0.0f;
#pragma unroll
    for (int c = 0; c < 8; ++c) {
      float wsel = (bits & (1u << c)) ? w1f[c] : 0.0f;
      xf = __fadd_rn(xf, wsel);
    }
    xbuf[(101 + t) * 64 + lane] = xf;
  }
  __syncthreads();

  const float arf = (float)0.6065306597126334;   // f32(exp(-0.5))
  const float Af  = (float)-27.182818284590452;  // f32(-10e)

// load group g's x fragment (8 b32) + taps (5 b128 + 1 b64): 14 DS ops
#define LOADGRP(g, xf_, kt_) do {                                         \
    const float* xg_ = xbuf + (96 + t0 - ((g) << 3)) * 64 + lane;         \
    _Pragma("unroll")                                                     \
    for (int u_ = 0; u_ < 8; ++u_) xf_[u_] = xg_[u_ * 64];                \
    const d2v* kp_ = (const d2v*)(kL + ((g) << 3));                       \
    _Pragma("unroll")                                                     \
    for (int u_ = 0; u_ < 5; ++u_) {                                      \
      d2v kv_ = kp_[u_];                                                  \
      kt_[2 * u_] = kv_.x; kt_[2 * u_ + 1] = kv_.y;                       \
    }                                                                     \
    kt_[10] = kL[((g) << 3) + 10];                                        \
  } while (0)

// FMA group: s descending == j ascending (canonical verified order)
#define FMAGRP(xf_, kt_) do {                                             \
    _Pragma("unroll")                                                     \
    for (int d_ = 0; d_ < 8; ++d_) {                                      \
      const double xv_ = (double)xf_[7 - d_];                             \
      a0 += kt_[d_ + 0] * xv_;                                            \
      a1 += kt_[d_ + 1] * xv_;                                            \
      a2 += kt_[d_ + 2] * xv_;                                            \
      a3 += kt_[d_ + 3] * xv_;                                            \
    }                                                                     \
  } while (0)

  // FIR for one chunk of 4 outputs t0..t0+3 (2-stage pipelined over groups)
  auto fir_chunk = [&](int s, int c, int bufsel) {
    const int t0 = 60 * s + 4 * c;
    double a0 = 0.0, a1 = 0.0, a2 = 0.0, a3 = 0.0;
    float  xfA[8], xfB[8];
    double ktA[11], ktB[11];
    LOADGRP(0, xfA, ktA);
#pragma clang loop unroll(disable)
    for (int g = 0; g < 12; g += 2) {
      LOADGRP(g + 1, xfB, ktB);
      FMAGRP(xfA, ktA);                    // waits counted: B's 14 DS in flight
      LOADGRP(g + 2, xfA, ktA);
      FMAGRP(xfB, ktB);
    }
    FMAGRP(xfA, ktA);                      // group 12
    float* ub = ubuf + bufsel * (60 * 64) + (4 * c) * 64 + lane;
    ub[0]   = (float)a0;
    ub[64]  = (float)a1;
    ub[128] = (float)a2;
    ub[192] = (float)a3;
  };

  float RX = 0.0f, RY = 0.0f;
  unsigned long long* maskW = maskG + (size_t)b * (5 * TLEN) + bh * TLEN;

  // scan one stage (wave 0 only; exact-f32 order as verified R2-R8)
  auto scan_stage = [&](int s) {
    const float* ub = ubuf + (s & 1) * (60 * 64) + lane;
#pragma clang loop unroll(disable)
    for (int r = 0; r < 60; r += 4) {
      float u0 = ub[(r + 0) * 64];
      float u1 = ub[(r + 1) * 64];
      float u2 = ub[(r + 2) * 64];
      float u3 = ub[(r + 3) * 64];
#pragma unroll
      for (int d = 0; d < 4; ++d) {
        float umem = (d == 0) ? u0 : (d == 1) ? u1 : (d == 2) ? u2 : u3;
        float v  = __fsub_rn(__fadd_rn(umem, RX), THETA);
        bool  sp = (v >= 0.0f) && (h < HID);
        unsigned long long bal = __ballot(sp);
        if (lane == 0) maskW[60 * s + r + d] = bal;
        float sf = sp ? 1.0f : 0.0f;
        float y2 = __fadd_rn(RY, __fmul_rn(Af, sf));
        RX = __fmul_rn(arf, __fadd_rn(RX, y2));
        RY = __fmul_rn(arf, y2);
      }
    }
  };

  // ---- 5-stage pipeline: scan(s) || fir(s+1); 15 chunks == 15 FIR waves ----
  if (wv < 15) fir_chunk(0, wv, 0);
  __syncthreads();
#pragma clang loop unroll(disable)
  for (int s = 0; s < 5; ++s) {
    if (wv == 0)      scan_stage(s);
    else if (s < 4)   fir_chunk(s + 1, wv - 1, (s + 1) & 1);
    __syncthreads();
  }
#undef LOADGRP
#undef FMAGRP
}

// ================== Kernel 2: layer-2 + head (per b) ======================
__global__ __launch_bounds__(320)
void snn_l2_kernel(const float* __restrict__ W2,
                   const unsigned long long* __restrict__ maskG,
                   float* __restrict__ out) {
  __shared__ double             kD[100];
  __shared__ double             W2D[2 * HID];
  __shared__ unsigned long long maskL[5 * TLEN];   // [5][300]
  __shared__ double             zD[2 * 304];
  __shared__ float              u2L[2 * 304];
  __shared__ float              lgL[2];

  const int tid = threadIdx.x;
  const int b   = blockIdx.x;

  const float arf = (float)0.6065306597126334;
  const float Af  = (float)-27.182818284590452;

  for (int j = tid; j < 100; j += 320) {
    float q  = (float)j / 10.0f;
    float ef = (float)exp((double)(1.0f - q));
    kD[j] = (double)__fmul_rn(q, ef);
  }
  for (int i = tid; i < 2 * HID; i += 320)
    W2D[i] = (double)W2[i];
  for (int i = tid; i < 5 * TLEN; i += 320)
    maskL[i] = maskG[(size_t)b * (5 * TLEN) + i];
  __syncthreads();

  // ---- fc2: flat ascending-h f64 chain, branchless (bit-identical) ----
  if (tid < TLEN) {
    const int t = tid;
    double z0 = 0.0, z1 = 0.0;
#pragma unroll
    for (int w5 = 0; w5 < 5; ++w5) {
      const unsigned long long mm = maskL[w5 * TLEN + t];
      const int kend = (w5 == 4) ? (HID - 256) : 64;
      for (int k = 0; k < kend; ++k) {
        const bool bit = (mm >> k) & 1ull;
        const int  hh  = w5 * 64 + k;
        z0 += bit ? W2D[hh] : 0.0;
        z1 += bit ? W2D[HID + hh] : 0.0;
      }
    }
    zD[t]       = (double)((float)z0);   // f32-rounded at tensor boundary
    zD[304 + t] = (double)((float)z1);
  }
  __syncthreads();

  // ---- psp2 (f64 accumulate, j ascending) ----
  if (tid < TLEN) {
    const int t = tid;
    double a0 = 0.0, a1 = 0.0;
    const int jmax = (t < KTAP) ? t : KTAP;
    for (int j = 1; j <= jmax; ++j) {
      const double kk = kD[j];
      a0 += kk * zD[t - j];
      a1 += kk * zD[304 + t - j];
    }
    u2L[t]       = (float)a0;
    u2L[304 + t] = (float)a1;
  }
  __syncthreads();

  // ---- layer-2 spike scan + count ----
  if (tid < 2) {
    float RX = 0.0f, RY = 0.0f;
    int cnt = 0;
    for (int t = 0; t < TLEN; ++t) {
      float u  = u2L[tid * 304 + t];
      float v  = __fsub_rn(__fadd_rn(u, RX), THETA);
      bool  sp = (v >= 0.0f);
      cnt += sp ? 1 : 0;
      float sf = sp ? 1.0f : 0.0f;
      float y2 = __fadd_rn(RY, __fmul_rn(Af, sf));
      RX = __fmul_rn(arf, __fadd_rn(RX, y2));
      RY = __fmul_rn(arf, y2);
    }
    lgL[tid] = (float)cnt;
  }
  __syncthreads();

  // ---- head (verified) ----
  if (tid == 0) {
    float l0 = lgL[0], l1 = lgL[1];
    uint32_t o0, o1;
    threefry2x32(0u, 2u * (uint32_t)b, o0, o1);
    float g0 = -logf(-logf(jax_uniform_from_bits(o0 ^ o1)));
    threefry2x32(0u, 2u * (uint32_t)b + 1u, o0, o1);
    float g1 = -logf(-logf(jax_uniform_from_bits(o0 ^ o1)));

    float v0 = __fadd_rn(l0, g0);
    float v1 = __fadd_rn(l1, g1);
    int   pi = (v1 > v0) ? 1 : 0;
    float m   = fmaxf(l0, l1);
    float s0f = __fsub_rn(l0, m), s1f = __fsub_rn(l1, m);
    float lse = logf(__fadd_rn(expf(s0f), expf(s1f)));
    float lp  = __fsub_rn(pi ? s1f : s0f, lse);

    out[2 * b + 0] = l0;
    out[2 * b + 1] = l1;
    out[2048 + b]  = (float)pi;
    out[3072 + b]  = lp;
  }
}

extern "C" void kernel_launch(void* const* d_in, const int* in_sizes, int n_in,
                              void* d_out, int out_size, void* d_ws, size_t ws_size,
                              hipStream_t stream) {
  const float* enc = (const float*)d_in[0];
  const float* W1  = (const float*)d_in[1];
  const float* W2  = (const float*)d_in[2];
  float* out = (float*)d_out;

  double*             tapsG = (double*)d_ws;                               // 856 B
  uint32_t*           encBG = (uint32_t*)((char*)d_ws + 1024);             // 1.23 MB
  unsigned long long* maskG = (unsigned long long*)((char*)d_ws + 1024 + 1228800);

  hipFuncSetAttribute((const void*)snn_l1_kernel,
                      hipFuncAttributeMaxDynamicSharedMemorySize, LDS_K1);

  snn_taps_kernel<<<dim3(1), dim3(128), 0, stream>>>(tapsG);
  snn_enc_kernel<<<dim3(NB), dim3(320), 0, stream>>>(enc, encBG);
  snn_l1_kernel<<<dim3(5, NB), dim3(1024), LDS_K1, stream>>>(W1, tapsG, encBG, maskG);
  snn_l2_kernel<<<dim3(NB), dim3(320), 0, stream>>>(W2, maskG, out);
}

// Round 10
// 799.388 us; speedup vs baseline: 1.0439x; 1.0439x over previous
//
#include <hip/hip_runtime.h>
#include <stdint.h>

// ---------------------------------------------------------------------------
// SNN categorical policy forward (B=1024, C_IN=8, HID=300, OUT=2, T=300)
//
// R10 = R8/R9 verified math + LDS-pipe relief (the measured bottleneck):
//  - xbuf stored quad-interleaved+transposed: xq[slot>>2][lane][slot&3].
//    Each group's 8 consecutive slots (base 96+t0-8g, always mult of 4)
//    load as 2 x ds_read_b128 (was 8 x ds_read_b32): DS-pipe cycles per
//    group 46 -> 24; the DS pipe (shared by 4 SIMDs/CU) was oversubscribed
//    ~2.5x in R9, ~1.1x in R8 -> now ~0.65.
//  - taps via s_load from global (SMEM pipe, R8-proven; R9's LDS taps
//    regressed by adding DS traffic).
//  - 5-stage scan/FIR overlap, 15 chunks == 15 FIR waves (R9 structure).
//  - enc pre-packed to bitmasks (R9 pre-kernel).
// Numerics byte-identical to verified R2-R9: same x f32 chain, same tap
// values/indices, same j-ascending f64 FMA order, same exact-f32 scans,
// same fc2/psp2/head. Only the LDS address function changed.
// ---------------------------------------------------------------------------

#define NB    1024
#define CIN   8
#define HID   300
#define TLEN  300
#define KTAP  99
#define THETA 10.0f

// K1 LDS layout (bytes):
//  xq   float[101 quads][64 lanes][4]   [0, 103424)
//  ubuf float[2][60*64]                 [103424, 134144)
#define LDS_K1 134144

typedef float f4 __attribute__((ext_vector_type(4)));

__device__ __forceinline__ void threefry2x32(uint32_t c0, uint32_t c1,
                                             uint32_t& o0, uint32_t& o1) {
  const uint32_t k0 = 0u, k1 = 42u;
  const uint32_t k2 = k0 ^ k1 ^ 0x1BD11BDAu;
  uint32_t x0 = c0 + k0, x1 = c1 + k1;
#define TFR(r) { x0 += x1; x1 = (x1 << (r)) | (x1 >> (32 - (r))); x1 ^= x0; }
  TFR(13) TFR(15) TFR(26) TFR(6)  x0 += k1; x1 += k2 + 1u;
  TFR(17) TFR(29) TFR(16) TFR(24) x0 += k2; x1 += k0 + 2u;
  TFR(13) TFR(15) TFR(26) TFR(6)  x0 += k0; x1 += k1 + 3u;
  TFR(17) TFR(29) TFR(16) TFR(24) x0 += k1; x1 += k2 + 4u;
  TFR(13) TFR(15) TFR(26) TFR(6)  x0 += k2; x1 += k0 + 5u;
#undef TFR
  o0 = x0; o1 = x1;
}

__device__ __forceinline__ float jax_uniform_from_bits(uint32_t bits) {
  uint32_t fb = (bits >> 9) | 0x3F800000u;
  float f = __uint_as_float(fb) - 1.0f;
  const float tiny = 1.17549435e-38f;
  float u = __fadd_rn(f, tiny);
  return fmaxf(tiny, u);
}

// ==================== Kernel 0a: taps -> global =============================
__global__ void snn_taps_kernel(double* __restrict__ tapsG) {
  const int i = threadIdx.x;
  if (i < 107) {
    const int j = i - 2;                 // tapsG[j+2] = kD[j], 0 outside [1,99]
    double v = 0.0;
    if (j >= 1 && j <= KTAP) {
      float q  = (float)j / 10.0f;
      float ef = (float)exp((double)(1.0f - q));   // same formula as R2-R9
      v = (double)__fmul_rn(q, ef);
    }
    tapsG[i] = v;
  }
}

// ==================== Kernel 0b: enc -> bitmask =============================
__global__ __launch_bounds__(320)
void snn_enc_kernel(const float* __restrict__ enc, uint32_t* __restrict__ encBG) {
  const int b = blockIdx.x, t = threadIdx.x;
  if (t < TLEN) {
    uint32_t m = 0u;
#pragma unroll
    for (int c = 0; c < CIN; ++c)
      if (enc[b * (CIN * TLEN) + c * TLEN + t] != 0.0f) m |= (1u << c);
    encBG[b * TLEN + t] = m;
  }
}

// ======================= Kernel 1: layer-1 SNN ============================
__global__ __launch_bounds__(1024, 1)
void snn_l1_kernel(const float* __restrict__ W1,
                   const double* __restrict__ tapsG,
                   const uint32_t* __restrict__ encBG,
                   unsigned long long* __restrict__ maskG) {
  extern __shared__ char smem[];
  float* xq   = (float*)(smem);              // quad-interleaved transposed x
  f4*    xqv  = (f4*)(smem);
  float* ubuf = (float*)(smem + 103424);

  const int tid  = threadIdx.x;
  const int lane = tid & 63;
  const int wv   = tid >> 6;            // wave 0..15
  const int bh   = blockIdx.x;          // h-chunk [0,5)
  const int b    = blockIdx.y;
  const int h    = bh * 64 + lane;

  // zero all of xq (covers zero history s<0; rest overwritten by phase A)
  for (int i = tid; i < 101 * 64; i += 1024)
    xqv[i] = (f4)(0.0f);
  __syncthreads();

  float w1f[8];
#pragma unroll
  for (int c = 0; c < 8; ++c)
    w1f[c] = (h < HID) ? W1[h * 8 + c] : 0.0f;

  // ---- phase A: x[t] for h=lane (bit-identical f32 add chain) ----
  // slot = 101 + t; write xq[slot>>2][lane][slot&3]
  for (int t = wv; t < TLEN; t += 16) {
    const uint32_t bits = encBG[__builtin_amdgcn_readfirstlane(b * TLEN + t)];
    float xf = 0.0f;
#pragma unroll
    for (int c = 0; c < 8; ++c) {
      float wsel = (bits & (1u << c)) ? w1f[c] : 0.0f;
      xf = __fadd_rn(xf, wsel);
    }
    const int slot = 101 + t;
    xq[(slot >> 2) * 256 + lane * 4 + (slot & 3)] = xf;
  }
  __syncthreads();

  const float arf = (float)0.6065306597126334;   // f32(exp(-0.5))
  const float Af  = (float)-27.182818284590452;  // f32(-10e)

  // FIR chunk of 4 outputs t0..t0+3; group g: slots [96+t0-8g, +8) = 2 quads,
  // taps tapsG[8g .. 8g+10] via s_load; FMA order identical to R8/R9.
  auto fir_chunk = [&](int s, int c, int bufsel) {
    const int t0 = 60 * s + 4 * c;
    double a0 = 0.0, a1 = 0.0, a2 = 0.0, a3 = 0.0;
#pragma clang loop unroll(disable)
    for (int g = 0; g < 13; ++g) {
      const int m0 = __builtin_amdgcn_readfirstlane(g << 3);
      const int qb = (96 + t0 - (g << 3)) >> 2;
      f4 v0 = xqv[qb * 64 + lane];                 // slots +0..3
      f4 v1 = xqv[(qb + 1) * 64 + lane];           // slots +4..7
      double kt[11];
#pragma unroll
      for (int u = 0; u < 11; ++u) kt[u] = tapsG[m0 + u];   // s_load (SMEM)
      double x64[8];
#pragma unroll
      for (int u = 0; u < 4; ++u) {
        x64[u]     = (double)v0[u];
        x64[4 + u] = (double)v1[u];
      }
#pragma unroll
      for (int d = 0; d < 8; ++d) {                // s desc == j asc (canonical)
        const double xv = x64[7 - d];
        a0 += kt[d + 0] * xv;
        a1 += kt[d + 1] * xv;
        a2 += kt[d + 2] * xv;
        a3 += kt[d + 3] * xv;
      }
    }
    float* ub = ubuf + bufsel * (60 * 64) + (4 * c) * 64 + lane;
    ub[0]   = (float)a0;
    ub[64]  = (float)a1;
    ub[128] = (float)a2;
    ub[192] = (float)a3;
  };

  float RX = 0.0f, RY = 0.0f;
  unsigned long long* maskW = maskG + (size_t)b * (5 * TLEN) + bh * TLEN;

  // scan one stage of 60 t (wave 0 only; exact-f32 order as verified)
  auto scan_stage = [&](int s) {
    const float* ub = ubuf + (s & 1) * (60 * 64) + lane;
#pragma clang loop unroll(disable)
    for (int r = 0; r < 60; r += 4) {
      float u0 = ub[(r + 0) * 64];
      float u1 = ub[(r + 1) * 64];
      float u2 = ub[(r + 2) * 64];
      float u3 = ub[(r + 3) * 64];
#pragma unroll
      for (int d = 0; d < 4; ++d) {
        float umem = (d == 0) ? u0 : (d == 1) ? u1 : (d == 2) ? u2 : u3;
        float v  = __fsub_rn(__fadd_rn(umem, RX), THETA);
        bool  sp = (v >= 0.0f) && (h < HID);
        unsigned long long bal = __ballot(sp);
        if (lane == 0) maskW[60 * s + r + d] = bal;
        float sf = sp ? 1.0f : 0.0f;
        float y2 = __fadd_rn(RY, __fmul_rn(Af, sf));
        RX = __fmul_rn(arf, __fadd_rn(RX, y2));
        RY = __fmul_rn(arf, y2);
      }
    }
  };

  // ---- 5-stage pipeline: scan(s) || fir(s+1); 15 chunks == 15 FIR waves ----
  if (wv < 15) fir_chunk(0, wv, 0);
  __syncthreads();
#pragma clang loop unroll(disable)
  for (int s = 0; s < 5; ++s) {
    if (wv == 0)      scan_stage(s);
    else if (s < 4)   fir_chunk(s + 1, wv - 1, (s + 1) & 1);
    __syncthreads();
  }
}

// ================== Kernel 2: layer-2 + head (per b) ======================
__global__ __launch_bounds__(320)
void snn_l2_kernel(const float* __restrict__ W2,
                   const unsigned long long* __restrict__ maskG,
                   float* __restrict__ out) {
  __shared__ double             kD[100];
  __shared__ double             W2D[2 * HID];
  __shared__ unsigned long long maskL[5 * TLEN];   // [5][300]
  __shared__ double             zD[2 * 304];
  __shared__ float              u2L[2 * 304];
  __shared__ float              lgL[2];

  const int tid = threadIdx.x;
  const int b   = blockIdx.x;

  const float arf = (float)0.6065306597126334;
  const float Af  = (float)-27.182818284590452;

  for (int j = tid; j < 100; j += 320) {
    float q  = (float)j / 10.0f;
    float ef = (float)exp((double)(1.0f - q));
    kD[j] = (double)__fmul_rn(q, ef);
  }
  for (int i = tid; i < 2 * HID; i += 320)
    W2D[i] = (double)W2[i];
  for (int i = tid; i < 5 * TLEN; i += 320)
    maskL[i] = maskG[(size_t)b * (5 * TLEN) + i];
  __syncthreads();

  // ---- fc2: flat ascending-h f64 chain, branchless (bit-identical) ----
  if (tid < TLEN) {
    const int t = tid;
    double z0 = 0.0, z1 = 0.0;
#pragma unroll
    for (int w5 = 0; w5 < 5; ++w5) {
      const unsigned long long mm = maskL[w5 * TLEN + t];
      const int kend = (w5 == 4) ? (HID - 256) : 64;
      for (int k = 0; k < kend; ++k) {
        const bool bit = (mm >> k) & 1ull;
        const int  hh  = w5 * 64 + k;
        z0 += bit ? W2D[hh] : 0.0;
        z1 += bit ? W2D[HID + hh] : 0.0;
      }
    }
    zD[t]       = (double)((float)z0);   // f32-rounded at tensor boundary
    zD[304 + t] = (double)((float)z1);
  }
  __syncthreads();

  // ---- psp2 (f64 accumulate, j ascending) ----
  if (tid < TLEN) {
    const int t = tid;
    double a0 = 0.0, a1 = 0.0;
    const int jmax = (t < KTAP) ? t : KTAP;
    for (int j = 1; j <= jmax; ++j) {
      const double kk = kD[j];
      a0 += kk * zD[t - j];
      a1 += kk * zD[304 + t - j];
    }
    u2L[t]       = (float)a0;
    u2L[304 + t] = (float)a1;
  }
  __syncthreads();

  // ---- layer-2 spike scan + count ----
  if (tid < 2) {
    float RX = 0.0f, RY = 0.0f;
    int cnt = 0;
    for (int t = 0; t < TLEN; ++t) {
      float u  = u2L[tid * 304 + t];
      float v  = __fsub_rn(__fadd_rn(u, RX), THETA);
      bool  sp = (v >= 0.0f);
      cnt += sp ? 1 : 0;
      float sf = sp ? 1.0f : 0.0f;
      float y2 = __fadd_rn(RY, __fmul_rn(Af, sf));
      RX = __fmul_rn(arf, __fadd_rn(RX, y2));
      RY = __fmul_rn(arf, y2);
    }
    lgL[tid] = (float)cnt;
  }
  __syncthreads();

  // ---- head (verified) ----
  if (tid == 0) {
    float l0 = lgL[0], l1 = lgL[1];
    uint32_t o0, o1;
    threefry2x32(0u, 2u * (uint32_t)b, o0, o1);
    float g0 = -logf(-logf(jax_uniform_from_bits(o0 ^ o1)));
    threefry2x32(0u, 2u * (uint32_t)b + 1u, o0, o1);
    float g1 = -logf(-logf(jax_uniform_from_bits(o0 ^ o1)));

    float v0 = __fadd_rn(l0, g0);
    float v1 = __fadd_rn(l1, g1);
    int   pi = (v1 > v0) ? 1 : 0;
    float m   = fmaxf(l0, l1);
    float s0f = __fsub_rn(l0, m), s1f = __fsub_rn(l1, m);
    float lse = logf(__fadd_rn(expf(s0f), expf(s1f)));
    float lp  = __fsub_rn(pi ? s1f : s0f, lse);

    out[2 * b + 0] = l0;
    out[2 * b + 1] = l1;
    out[2048 + b]  = (float)pi;
    out[3072 + b]  = lp;
  }
}

extern "C" void kernel_launch(void* const* d_in, const int* in_sizes, int n_in,
                              void* d_out, int out_size, void* d_ws, size_t ws_size,
                              hipStream_t stream) {
  const float* enc = (const float*)d_in[0];
  const float* W1  = (const float*)d_in[1];
  const float* W2  = (const float*)d_in[2];
  float* out = (float*)d_out;

  double*             tapsG = (double*)d_ws;                               // 856 B
  uint32_t*           encBG = (uint32_t*)((char*)d_ws + 1024);             // 1.23 MB
  unsigned long long* maskG = (unsigned long long*)((char*)d_ws + 1024 + 1228800);

  hipFuncSetAttribute((const void*)snn_l1_kernel,
                      hipFuncAttributeMaxDynamicSharedMemorySize, LDS_K1);

  snn_taps_kernel<<<dim3(1), dim3(128), 0, stream>>>(tapsG);
  snn_enc_kernel<<<dim3(NB), dim3(320), 0, stream>>>(enc, encBG);
  snn_l1_kernel<<<dim3(5, NB), dim3(1024), LDS_K1, stream>>>(W1, tapsG, encBG, maskG);
  snn_l2_kernel<<<dim3(NB), dim3(320), 0, stream>>>(W2, maskG, out);
}

// Round 11
// 777.294 us; speedup vs baseline: 1.0736x; 1.0284x over previous
//
#include <hip/hip_runtime.h>
#include <stdint.h>

// ---------------------------------------------------------------------------
// SNN categorical policy forward (B=1024, C_IN=8, HID=300, OUT=2, T=300)
//
// R11 = R10 verified math + a pipeline that can actually engage:
//  - taps via VMEM global_load (opaque-zero VGPR offset) -> vmcnt (in-order,
//    counted); x via ds_read_b128 -> lgkmcnt (in-order, counted). No SMEM in
//    the loop => no forced lgkmcnt(0) drains (R10's serializer).
//  - manual 2-deep A/B software pipeline over tap groups, pinned with
//    sched_barrier(0) (R9/R10: scheduler re-serialized to VGPR=20/40).
//  - TB=8 outputs/chunk: 64 FMA per group window (was 32).
//  - phase A: per-lane b128 quad writes (kills 9.2M bank conflicts).
//  - tail group computes only j=97..99 (zero-tap terms were exact no-ops).
// Numerics bit-identical to verified R2-R10: per-acc f64 FMA chain is
// j=1..99 ascending with the same f32-rounded taps; exact-f32 scans; f64
// fc2; partitionable threefry head.
// ---------------------------------------------------------------------------

#define NB    1024
#define CIN   8
#define HID   300
#define TLEN  300
#define KTAP  99
#define THETA 10.0f

// K1 LDS layout (bytes):
//  xq   f4[102 quads][64 lanes]   [0, 104448)      slot = s + 104
//  ubuf float[2][56*64]           [104448, 133120)
#define LDS_K1 133120

typedef float  f4  __attribute__((ext_vector_type(4)));
typedef double d2v __attribute__((ext_vector_type(2)));

__device__ __forceinline__ void threefry2x32(uint32_t c0, uint32_t c1,
                                             uint32_t& o0, uint32_t& o1) {
  const uint32_t k0 = 0u, k1 = 42u;
  const uint32_t k2 = k0 ^ k1 ^ 0x1BD11BDAu;
  uint32_t x0 = c0 + k0, x1 = c1 + k1;
#define TFR(r) { x0 += x1; x1 = (x1 << (r)) | (x1 >> (32 - (r))); x1 ^= x0; }
  TFR(13) TFR(15) TFR(26) TFR(6)  x0 += k1; x1 += k2 + 1u;
  TFR(17) TFR(29) TFR(16) TFR(24) x0 += k2; x1 += k0 + 2u;
  TFR(13) TFR(15) TFR(26) TFR(6)  x0 += k0; x1 += k1 + 3u;
  TFR(17) TFR(29) TFR(16) TFR(24) x0 += k1; x1 += k2 + 4u;
  TFR(13) TFR(15) TFR(26) TFR(6)  x0 += k2; x1 += k0 + 5u;
#undef TFR
  o0 = x0; o1 = x1;
}

__device__ __forceinline__ float jax_uniform_from_bits(uint32_t bits) {
  uint32_t fb = (bits >> 9) | 0x3F800000u;
  float f = __uint_as_float(fb) - 1.0f;
  const float tiny = 1.17549435e-38f;
  float u = __fadd_rn(f, tiny);
  return fmaxf(tiny, u);
}

// ==================== Kernel 0a: shifted taps -> global =====================
// tapsP[i] = k_{i+1} (f32-rounded, same formula as all verified rounds);
// tapsP[99..103] = 0.
__global__ void snn_taps_kernel(double* __restrict__ tapsP) {
  const int i = threadIdx.x;
  if (i < 104) {
    const int j = i + 1;
    double v = 0.0;
    if (j <= KTAP) {
      float q  = (float)j / 10.0f;
      float ef = (float)exp((double)(1.0f - q));
      v = (double)__fmul_rn(q, ef);
    }
    tapsP[i] = v;
  }
}

// ==================== Kernel 0b: enc -> bitmask =============================
__global__ __launch_bounds__(320)
void snn_enc_kernel(const float* __restrict__ enc, uint32_t* __restrict__ encBG) {
  const int b = blockIdx.x, t = threadIdx.x;
  if (t < TLEN) {
    uint32_t m = 0u;
#pragma unroll
    for (int c = 0; c < CIN; ++c)
      if (enc[b * (CIN * TLEN) + c * TLEN + t] != 0.0f) m |= (1u << c);
    encBG[b * TLEN + t] = m;
  }
}

// ======================= Kernel 1: layer-1 SNN ============================
__global__ __launch_bounds__(1024, 1)
void snn_l1_kernel(const float* __restrict__ W1,
                   const double* __restrict__ tapsP,
                   const uint32_t* __restrict__ encBG,
                   unsigned long long* __restrict__ maskG) {
  extern __shared__ char smem[];
  f4*    xqv  = (f4*)(smem);                 // [102*64]
  float* ubuf = (float*)(smem + 104448);     // [2][56*64]

  const int tid  = threadIdx.x;
  const int lane = tid & 63;
  const int wv   = tid >> 6;            // wave 0..15
  const int bh   = blockIdx.x;          // h-chunk [0,5)
  const int b    = blockIdx.y;
  const int h    = bh * 64 + lane;

  // opaque zero in a VGPR: forces tap loads to VMEM (vmcnt), not SMEM
  int vzero;
  asm volatile("v_mov_b32 %0, 0" : "=v"(vzero));

  float w1f[8];
#pragma unroll
  for (int c = 0; c < 8; ++c)
    w1f[c] = (h < HID) ? W1[h * 8 + c] : 0.0f;

  // ---- phase A: x -> xq, one f4 quad per (q, own-lane) task --------------
  // quad q holds slots 4q..4q+3; slot = t + 104; t<0 / t>=300 -> exact +0.
#pragma clang loop unroll(disable)
  for (int q = wv; q < 102; q += 16) {
    f4 v;
#pragma unroll
    for (int o = 0; o < 4; ++o) {
      const int t = (q << 2) + o - 104;
      float xf = 0.0f;
      if (t >= 0 && t < TLEN) {
        const uint32_t bits = encBG[__builtin_amdgcn_readfirstlane(b * TLEN + t)];
#pragma unroll
        for (int c = 0; c < 8; ++c)
          xf = __fadd_rn(xf, (bits & (1u << c)) ? w1f[c] : 0.0f);
      }
      v[o] = xf;
    }
    xqv[q * 64 + lane] = v;                  // b128 write, conflict-free
  }
  __syncthreads();

  const float arf = (float)0.6065306597126334;   // f32(exp(-0.5))
  const float Af  = (float)-27.182818284590452;  // f32(-10e)

// group g covers j = 8g+1 .. 8g+8 (tail g=12: j=97..99). x slots for outputs
// t0..t0+7: s in [t0-8g-8, t0-8g+6] -> 4 quads from qb = (t0-8g+96)>>2.
#define LOADG(g_, x0_, x1_, x2_, x3_, k0_, k1_, k2_, k3_) do {            \
    const int qb_ = ((t0 - ((g_) << 3) + 96) >> 2) * 64 + lane;           \
    x0_ = xqv[qb_];        x1_ = xqv[qb_ + 64];                           \
    x2_ = xqv[qb_ + 128];  x3_ = xqv[qb_ + 192];                          \
    const d2v* tp_ = (const d2v*)(tapsP) + (((g_) << 2) + vzero);         \
    k0_ = tp_[0]; k1_ = tp_[1]; k2_ = tp_[2]; k3_ = tp_[3];               \
  } while (0)

// FMA: e ascending == j ascending per accumulator (canonical verified chain)
#define FMAG(EMAX, x0_, x1_, x2_, x3_, k0_, k1_, k2_, k3_) do {           \
    double x64_[16];                                                      \
    _Pragma("unroll")                                                     \
    for (int o_ = 0; o_ < 4; ++o_) {                                      \
      x64_[o_]      = (double)x0_[o_];                                    \
      x64_[4 + o_]  = (double)x1_[o_];                                    \
      x64_[8 + o_]  = (double)x2_[o_];                                    \
      x64_[12 + o_] = (double)x3_[o_];                                    \
    }                                                                     \
    double kt_[8];                                                        \
    kt_[0] = k0_[0]; kt_[1] = k0_[1]; kt_[2] = k1_[0]; kt_[3] = k1_[1];   \
    kt_[4] = k2_[0]; kt_[5] = k2_[1]; kt_[6] = k3_[0]; kt_[7] = k3_[1];   \
    _Pragma("unroll")                                                     \
    for (int e_ = 0; e_ <= (EMAX); ++e_) {                                \
      const double kk_ = kt_[e_];                                         \
      _Pragma("unroll")                                                   \
      for (int i_ = 0; i_ < 8; ++i_)                                      \
        acc[i_] += kk_ * x64_[i_ - e_ + 7];                               \
    }                                                                     \
  } while (0)

  // FIR for one chunk of 8 outputs, 2-deep A/B pipelined over 13 groups
  auto fir_chunk = [&](int sbase, int cl, int bufsel) {
    const int t0 = sbase + (cl << 3);
    double acc[8];
#pragma unroll
    for (int i = 0; i < 8; ++i) acc[i] = 0.0;

    f4  xa0, xa1, xa2, xa3, xb0, xb1, xb2, xb3;
    d2v ka0, ka1, ka2, ka3, kb0, kb1, kb2, kb3;

    LOADG(0, xa0, xa1, xa2, xa3, ka0, ka1, ka2, ka3);
    __builtin_amdgcn_sched_barrier(0);
#pragma clang loop unroll(disable)
    for (int g = 0; g < 12; g += 2) {
      LOADG(g + 1, xb0, xb1, xb2, xb3, kb0, kb1, kb2, kb3);
      __builtin_amdgcn_sched_barrier(0);
      FMAG(7, xa0, xa1, xa2, xa3, ka0, ka1, ka2, ka3);
      __builtin_amdgcn_sched_barrier(0);
      LOADG(g + 2, xa0, xa1, xa2, xa3, ka0, ka1, ka2, ka3);
      __builtin_amdgcn_sched_barrier(0);
      FMAG(7, xb0, xb1, xb2, xb3, kb0, kb1, kb2, kb3);
      __builtin_amdgcn_sched_barrier(0);
    }
    FMAG(2, xa0, xa1, xa2, xa3, ka0, ka1, ka2, ka3);   // g=12: j=97,98,99

    float* ub = ubuf + bufsel * (56 * 64) + (cl << 3) * 64 + lane;
#pragma unroll
    for (int i = 0; i < 8; ++i)
      ub[i * 64] = (float)acc[i];
  };

  float RX = 0.0f, RY = 0.0f;
  unsigned long long* maskW = maskG + (size_t)b * (5 * TLEN) + bh * TLEN;

  // scan one stage (wave 0 only; exact-f32 order as verified)
  auto scan_stage = [&](int s) {
    const int tlen = (s == 5) ? 20 : 56;     // stage 5 covers t 280..299
    const float* ub = ubuf + (s & 1) * (56 * 64) + lane;
#pragma clang loop unroll(disable)
    for (int r = 0; r < tlen; r += 4) {
      float u0 = ub[(r + 0) * 64];
      float u1 = ub[(r + 1) * 64];
      float u2 = ub[(r + 2) * 64];
      float u3 = ub[(r + 3) * 64];
#pragma unroll
      for (int d = 0; d < 4; ++d) {
        float umem = (d == 0) ? u0 : (d == 1) ? u1 : (d == 2) ? u2 : u3;
        float v  = __fsub_rn(__fadd_rn(umem, RX), THETA);
        bool  sp = (v >= 0.0f) && (h < HID);
        unsigned long long bal = __ballot(sp);
        if (lane == 0) maskW[56 * s + r + d] = bal;
        float sf = sp ? 1.0f : 0.0f;
        float y2 = __fadd_rn(RY, __fmul_rn(Af, sf));
        RX = __fmul_rn(arf, __fadd_rn(RX, y2));
        RY = __fmul_rn(arf, y2);
      }
    }
  };

  // ---- 6-stage pipeline: scan(s) || fir(s+1) ----
  // stages: 5 x 56t (7 chunks) + 1 x 24t (3 chunks, scan clipped to 20t)
  if (wv < 7) fir_chunk(0, wv, 0);
  __syncthreads();
#pragma clang loop unroll(disable)
  for (int s = 0; s < 6; ++s) {
    if (wv == 0) {
      scan_stage(s);
    } else if (s < 5) {
      const int nc = (s + 1 == 5) ? 3 : 7;
      if (wv - 1 < nc) fir_chunk(56 * (s + 1), wv - 1, (s + 1) & 1);
    }
    __syncthreads();
  }
#undef LOADG
#undef FMAG
}

// ================== Kernel 2: layer-2 + head (per b) ======================
__global__ __launch_bounds__(320)
void snn_l2_kernel(const float* __restrict__ W2,
                   const unsigned long long* __restrict__ maskG,
                   float* __restrict__ out) {
  __shared__ double             kD[100];
  __shared__ double             W2D[2 * HID];
  __shared__ unsigned long long maskL[5 * TLEN];   // [5][300]
  __shared__ double             zD[2 * 304];
  __shared__ float              u2L[2 * 304];
  __shared__ float              lgL[2];

  const int tid = threadIdx.x;
  const int b   = blockIdx.x;

  const float arf = (float)0.6065306597126334;
  const float Af  = (float)-27.182818284590452;

  for (int j = tid; j < 100; j += 320) {
    float q  = (float)j / 10.0f;
    float ef = (float)exp((double)(1.0f - q));
    kD[j] = (double)__fmul_rn(q, ef);
  }
  for (int i = tid; i < 2 * HID; i += 320)
    W2D[i] = (double)W2[i];
  for (int i = tid; i < 5 * TLEN; i += 320)
    maskL[i] = maskG[(size_t)b * (5 * TLEN) + i];
  __syncthreads();

  // ---- fc2: flat ascending-h f64 chain, branchless (bit-identical) ----
  if (tid < TLEN) {
    const int t = tid;
    double z0 = 0.0, z1 = 0.0;
#pragma unroll
    for (int w5 = 0; w5 < 5; ++w5) {
      const unsigned long long mm = maskL[w5 * TLEN + t];
      const int kend = (w5 == 4) ? (HID - 256) : 64;
      for (int k = 0; k < kend; ++k) {
        const bool bit = (mm >> k) & 1ull;
        const int  hh  = w5 * 64 + k;
        z0 += bit ? W2D[hh] : 0.0;
        z1 += bit ? W2D[HID + hh] : 0.0;
      }
    }
    zD[t]       = (double)((float)z0);   // f32-rounded at tensor boundary
    zD[304 + t] = (double)((float)z1);
  }
  __syncthreads();

  // ---- psp2 (f64 accumulate, j ascending) ----
  if (tid < TLEN) {
    const int t = tid;
    double a0 = 0.0, a1 = 0.0;
    const int jmax = (t < KTAP) ? t : KTAP;
    for (int j = 1; j <= jmax; ++j) {
      const double kk = kD[j];
      a0 += kk * zD[t - j];
      a1 += kk * zD[304 + t - j];
    }
    u2L[t]       = (float)a0;
    u2L[304 + t] = (float)a1;
  }
  __syncthreads();

  // ---- layer-2 spike scan + count ----
  if (tid < 2) {
    float RX = 0.0f, RY = 0.0f;
    int cnt = 0;
    for (int t = 0; t < TLEN; ++t) {
      float u  = u2L[tid * 304 + t];
      float v  = __fsub_rn(__fadd_rn(u, RX), THETA);
      bool  sp = (v >= 0.0f);
      cnt += sp ? 1 : 0;
      float sf = sp ? 1.0f : 0.0f;
      float y2 = __fadd_rn(RY, __fmul_rn(Af, sf));
      RX = __fmul_rn(arf, __fadd_rn(RX, y2));
      RY = __fmul_rn(arf, y2);
    }
    lgL[tid] = (float)cnt;
  }
  __syncthreads();

  // ---- head (verified) ----
  if (tid == 0) {
    float l0 = lgL[0], l1 = lgL[1];
    uint32_t o0, o1;
    threefry2x32(0u, 2u * (uint32_t)b, o0, o1);
    float g0 = -logf(-logf(jax_uniform_from_bits(o0 ^ o1)));
    threefry2x32(0u, 2u * (uint32_t)b + 1u, o0, o1);
    float g1 = -logf(-logf(jax_uniform_from_bits(o0 ^ o1)));

    float v0 = __fadd_rn(l0, g0);
    float v1 = __fadd_rn(l1, g1);
    int   pi = (v1 > v0) ? 1 : 0;
    float m   = fmaxf(l0, l1);
    float s0f = __fsub_rn(l0, m), s1f = __fsub_rn(l1, m);
    float lse = logf(__fadd_rn(expf(s0f), expf(s1f)));
    float lp  = __fsub_rn(pi ? s1f : s0f, lse);

    out[2 * b + 0] = l0;
    out[2 * b + 1] = l1;
    out[2048 + b]  = (float)pi;
    out[3072 + b]  = lp;
  }
}

extern "C" void kernel_launch(void* const* d_in, const int* in_sizes, int n_in,
                              void* d_out, int out_size, void* d_ws, size_t ws_size,
                              hipStream_t stream) {
  const float* enc = (const float*)d_in[0];
  const float* W1  = (const float*)d_in[1];
  const float* W2  = (const float*)d_in[2];
  float* out = (float*)d_out;

  double*             tapsP = (double*)d_ws;                               // 832 B
  uint32_t*           encBG = (uint32_t*)((char*)d_ws + 1024);             // 1.23 MB
  unsigned long long* maskG = (unsigned long long*)((char*)d_ws + 1024 + 1228800);

  hipFuncSetAttribute((const void*)snn_l1_kernel,
                      hipFuncAttributeMaxDynamicSharedMemorySize, LDS_K1);

  snn_taps_kernel<<<dim3(1), dim3(128), 0, stream>>>(tapsP);
  snn_enc_kernel<<<dim3(NB), dim3(320), 0, stream>>>(enc, encBG);
  snn_l1_kernel<<<dim3(5, NB), dim3(1024), LDS_K1, stream>>>(W1, tapsP, encBG, maskG);
  snn_l2_kernel<<<dim3(NB), dim3(320), 0, stream>>>(W2, maskG, out);
}